// Round 12
// baseline (2331.522 us; speedup 1.0000x reference)
//
#include <hip/hip_runtime.h>
#include <cmath>
#include <cfloat>

#define DEV __device__ __forceinline__

DEV unsigned enc_f(float x) { unsigned u = __float_as_uint(x); return (u >> 31) ? ~u : (u | 0x80000000u); }
DEV float dec_f(unsigned u) { return __uint_as_float((u >> 31) ? (u & 0x7FFFFFFFu) : ~u); }

// release-signal / acquire-spin primitives (device scope; cross-XCD safe)
DEV void bar_signal(unsigned* p) {
    __threadfence();
    __hip_atomic_fetch_add(p, 1u, __ATOMIC_RELEASE, __HIP_MEMORY_SCOPE_AGENT);
}
DEV void bar_wait(unsigned* p, unsigned tgt) {
    while (__hip_atomic_load(p, __ATOMIC_ACQUIRE, __HIP_MEMORY_SCOPE_AGENT) < tgt)
        __builtin_amdgcn_s_sleep(2);
}

// ---------------- mega0: interleaved degree-count + layer-0 GEMM + encoder ----------------
// Round-10's contiguous-range mega serialized (in-order dispatch). Interleave instead:
// b%3==0 -> gemm0 tile b/3 (VALU-bound); b%3 in {1,2} -> count block (latency-bound
// atomics). Resident set always holds a mix -> pipes overlap. Encoder = last block.
__global__ __launch_bounds__(256) void mega0_kernel(
    const int* __restrict__ dst, int* __restrict__ deg, int E, int N,
    int nCount, int gblocks,
    const int* __restrict__ ids, const float* __restrict__ rssi,
    const float* __restrict__ emb, const float* __restrict__ ew, const float* __restrict__ eb,
    const float* __restrict__ Wl0, const float* __restrict__ Wr0, const float* __restrict__ b0,
    float* __restrict__ zout, int NQ,
    const float* __restrict__ A, float* __restrict__ O1, float* __restrict__ O2)
{
    __shared__ float As[64][36];
    __shared__ float Bs[32][128];
    const int tid = threadIdx.x;
    const int b = blockIdx.x;
    const int T = 3 * gblocks;

    if (b == (int)gridDim.x - 1) {
        // ---- encoder: zout = { z_q, cl = zq@Wl0_bot, crb = zq@Wr0_bot + b0 } ----
        float* zsh = &As[0][0];          // 4*64
        float* zq  = &As[0][0] + 256;
        int j = tid & 63, g = tid >> 6;
        float acc = 0.f;
        for (int q = g; q < NQ; q += 4) {
            int id = ids[q];
            const float* e = emb + (size_t)id * 32;
            float p = eb[j];
#pragma unroll
            for (int k = 0; k < 32; ++k) p = fmaf(e[k], ew[k * 64 + j], p);
            p = fmaf(rssi[q], ew[32 * 64 + j], p);
            acc += fmaxf(p, 0.f);
        }
        zsh[g * 64 + j] = acc;
        __syncthreads();
        if (g == 0) {
            float z = (zsh[j] + zsh[64 + j] + zsh[128 + j] + zsh[192 + j]) / (float)NQ;
            zq[j] = z;
            zout[j] = z;
        }
        __syncthreads();
        if (g == 0) {
            float cl = 0.f, cr = 0.f;
            for (int k = 0; k < 64; ++k) {
                float zk = zq[k];
                cl = fmaf(zk, Wl0[(128 + k) * 64 + j], cl);
                cr = fmaf(zk, Wr0[(128 + k) * 64 + j], cr);
            }
            zout[64 + j] = cl;
            zout[128 + j] = cr + b0[j];
        }
        return;
    }

    int gemmIdx = -1, cntIdx = -1;
    if (b < T) {
        int q = b / 3, r = b % 3;
        if (r == 0) gemmIdx = q;
        else cntIdx = q * 2 + (r - 1);
    } else {
        cntIdx = 2 * gblocks + (b - T);
    }

    if (cntIdx >= 0) {
        if (cntIdx >= nCount) return;
        const int part = cntIdx & 7;
        const int chunk = cntIdx >> 3;
        const int npart = (N + 7) >> 3;
        const int lo = part * npart;
        const int hi = min(lo + npart, N);
        const int base = chunk * 4096 + tid;
#pragma unroll
        for (int it = 0; it < 16; ++it) {
            int i = base + it * 256;
            if (i < E) {
                int d = dst[i];
                if (d >= lo && d < hi) atomicAdd(&deg[d], 1);
            }
        }
        return;
    }

    // ---- layer-0 GEMM tile: O1 = x@Wl0_top, O2 = x@Wr0_top (crb/b0 added in agg0) ----
    constexpr int K = 128;
    const int cg = tid & 31;
    const int rg = tid >> 5;
    const int row0 = gemmIdx * 64;

    float acc[8][4];
#pragma unroll
    for (int i = 0; i < 8; ++i)
#pragma unroll
        for (int j = 0; j < 4; ++j) acc[i][j] = 0.f;

    for (int kc = 0; kc < K; kc += 32) {
#pragma unroll
        for (int i = 0; i < 2; ++i) {
            int vi = i * 256 + tid;
            int rr = vi >> 3;
            int k4 = (vi & 7) << 2;
            int row = row0 + rr;
            float4 v = make_float4(0.f, 0.f, 0.f, 0.f);
            if (row < N) v = *(const float4*)(A + (size_t)row * K + kc + k4);
            As[rr][k4 + 0] = v.x; As[rr][k4 + 1] = v.y; As[rr][k4 + 2] = v.z; As[rr][k4 + 3] = v.w;
        }
#pragma unroll
        for (int i = 0; i < 4; ++i) {
            int vi = i * 256 + tid;
            int k = vi >> 5;
            int c = (vi & 31) << 2;
            const float* sp = (c < 64) ? (Wl0 + (size_t)(kc + k) * 64 + c)
                                       : (Wr0 + (size_t)(kc + k) * 64 + (c - 64));
            *(float4*)&Bs[k][c] = *(const float4*)sp;
        }
        __syncthreads();
#pragma unroll
        for (int k4 = 0; k4 < 32; k4 += 4) {
            float4 a4[8];
#pragma unroll
            for (int i = 0; i < 8; ++i)
                a4[i] = *(const float4*)&As[rg * 8 + i][k4];
            float4 bv[4];
#pragma unroll
            for (int j = 0; j < 4; ++j)
                bv[j] = *(const float4*)&Bs[k4 + j][cg * 4];
#pragma unroll
            for (int j = 0; j < 4; ++j) {
#pragma unroll
                for (int i = 0; i < 8; ++i) {
                    float av = ((const float*)&a4[i])[j];
                    acc[i][0] = fmaf(av, bv[j].x, acc[i][0]);
                    acc[i][1] = fmaf(av, bv[j].y, acc[i][1]);
                    acc[i][2] = fmaf(av, bv[j].z, acc[i][2]);
                    acc[i][3] = fmaf(av, bv[j].w, acc[i][3]);
                }
            }
        }
        __syncthreads();
    }

    int c0 = cg * 4;
    float* O; int c;
    if (c0 < 64) { O = O1; c = c0; }
    else         { O = O2; c = c0 - 64; }
#pragma unroll
    for (int i = 0; i < 8; ++i) {
        int row = row0 + rg * 8 + i;
        if (row < N) {
            float4 o = make_float4(acc[i][0], acc[i][1], acc[i][2], acc[i][3]);
            *(float4*)(O + (size_t)row * 64 + c) = o;
        }
    }
}

// ---------------- merged CSR scan: local scan + grid barrier + chunk scan + apply ----------------
// NB (=196) blocks, all co-resident (<256 CUs); two spin barriers (bar[0], bar[1], zeroed by memset).
__global__ __launch_bounds__(256) void scan_kernel(
    const int* __restrict__ deg, int* __restrict__ offs, int* __restrict__ cursor,
    int* __restrict__ bsum, int* __restrict__ bbase, unsigned* __restrict__ bar,
    int N, int NB)
{
    __shared__ int sh[256];
    int t = threadIdx.x;
    int i = blockIdx.x * 256 + t;
    int v = (i < N) ? deg[i] : 0;
    sh[t] = v;
    __syncthreads();
#pragma unroll
    for (int d = 1; d < 256; d <<= 1) {
        int u = (t >= d) ? sh[t - d] : 0;
        __syncthreads();
        sh[t] += u;
        __syncthreads();
    }
    if (i < N) offs[i] = sh[t] - v;
    if (t == 255) bsum[blockIdx.x] = sh[255];

    __syncthreads();
    if (t == 0) { bar_signal(&bar[0]); bar_wait(&bar[0], (unsigned)NB); }
    __syncthreads();

    if (blockIdx.x == 0) {
        int bv = (t < NB) ? bsum[t] : 0;
        sh[t] = bv;
        __syncthreads();
#pragma unroll
        for (int d = 1; d < 256; d <<= 1) {
            int u = (t >= d) ? sh[t - d] : 0;
            __syncthreads();
            sh[t] += u;
            __syncthreads();
        }
        if (t < NB) bbase[t] = sh[t] - bv;
        if (t == 255) offs[N] = sh[255];
    }

    __syncthreads();
    if (t == 0) { bar_signal(&bar[1]); bar_wait(&bar[1], (unsigned)NB); }
    __syncthreads();

    if (i < N) {
        int o = offs[i] + bbase[blockIdx.x];
        offs[i] = o;
        cursor[i] = o;
    }
}

// XCD-partitioned scatter (round-2 win): one XCD owns each srcs region.
__global__ __launch_bounds__(256) void scatter_kernel(const int* __restrict__ src, const int* __restrict__ dst,
                                                      int* __restrict__ cursor, int* __restrict__ srcs,
                                                      int E, int N)
{
    const int part = blockIdx.x & 7;
    const int chunk = blockIdx.x >> 3;
    const int npart = (N + 7) >> 3;
    const int lo = part * npart;
    const int hi = min(lo + npart, N);
    const int base = chunk * 4096 + threadIdx.x;
#pragma unroll
    for (int it = 0; it < 16; ++it) {
        int i = base + it * 256;
        if (i < E) {
            int d = dst[i];
            if (d >= lo && d < hi) {
                int p = atomicAdd(&cursor[d], 1);
                srcs[p] = src[i];
            }
        }
    }
}

// ---------------- agg block body (shared by layer / final kernels) ----------------
DEV void agg_body(const float* __restrict__ m, const float* __restrict__ r,
                  const int* __restrict__ offs, const int* __restrict__ srcs,
                  const float* __restrict__ cl, const float* __restrict__ addv,
                  float* __restrict__ h, int N, int a, int tid)
{
    int lane = tid & 63, sub = tid >> 6;
    int node = a * 4 + sub;
    if (node < N) {
        int e0 = offs[node], e1 = offs[node + 1];
        float acc[16];
#pragma unroll
        for (int i = 0; i < 16; ++i) acc[i] = 0.f;
        for (int base = e0; base < e1; base += 64) {
            int e = base + lane;
            int sv = (e < e1) ? srcs[e] : 0;
            int cnt = min(e1 - base, 64);
            int q = 0;
            for (; q + 16 <= cnt; q += 16) {
#pragma unroll
                for (int u = 0; u < 16; ++u) {
                    int s = __shfl(sv, q + u);
                    acc[u] += m[(size_t)s * 64 + lane];
                }
            }
            for (; q + 4 <= cnt; q += 4) {
#pragma unroll
                for (int u = 0; u < 4; ++u) {
                    int s = __shfl(sv, q + u);
                    acc[u] += m[(size_t)s * 64 + lane];
                }
            }
            for (; q < cnt; ++q) {
                int s = __shfl(sv, q);
                acc[0] += m[(size_t)s * 64 + lane];
            }
        }
        float sum = 0.f;
#pragma unroll
        for (int i = 0; i < 16; ++i) sum += acc[i];
        int degn = e1 - e0;
        float v = sum / (float)(degn > 0 ? degn : 1) + r[(size_t)node * 64 + lane];
        if (addv != nullptr) v += addv[lane];
        if (cl != nullptr && degn > 0) v += cl[lane];
        h[(size_t)node * 64 + lane] = fmaxf(v, 0.f);
    }
}

// ---------------- producer-consumer layer: agg_L (16 blocks/tile) + gemm_{L+1} (1 block/tile) ----
// Block 17t+j, j<16: agg block a=16t+j -> writes h rows, signals tf[t] (release).
// Block 17t+16: spins (acquire) until all of tile t's h rows are ready, then K=64 GEMM.
// gemm only waits on SMALLER blockIdx -> in-order dispatch guarantees progress (no deadlock).
__global__ __launch_bounds__(256) void layer_kernel(
    const float* __restrict__ m, const float* __restrict__ r,
    const int* __restrict__ offs, const int* __restrict__ srcs,
    const float* __restrict__ cl, const float* __restrict__ addv,
    float* __restrict__ h,
    const float* __restrict__ B1, const float* __restrict__ B2, const float* __restrict__ add2,
    float* __restrict__ O1, float* __restrict__ O2,
    unsigned* __restrict__ tf, int N)
{
    __shared__ float As[64][36];
    __shared__ float Bs[32][128];
    const int tid = threadIdx.x;
    const int t = blockIdx.x / 17;
    const int j = blockIdx.x % 17;

    if (j < 16) {
        int a = 16 * t + j;
        if (a * 4 >= N) return;
        agg_body(m, r, offs, srcs, cl, addv, h, N, a, tid);
        __syncthreads();
        if (tid == 0) bar_signal(&tf[t]);
        return;
    }

    const int row0 = t * 64;
    unsigned expected = (unsigned)((min(64, N - row0) + 3) >> 2);
    if (tid == 0) bar_wait(&tf[t], expected);
    __syncthreads();

    const int cg = tid & 31;
    const int rg = tid >> 5;
    float acc[8][4];
#pragma unroll
    for (int i = 0; i < 8; ++i)
#pragma unroll
        for (int jj = 0; jj < 4; ++jj) acc[i][jj] = 0.f;

    for (int kc = 0; kc < 64; kc += 32) {
#pragma unroll
        for (int i = 0; i < 2; ++i) {
            int vi = i * 256 + tid;
            int rr = vi >> 3;
            int k4 = (vi & 7) << 2;
            int row = row0 + rr;
            float4 v = make_float4(0.f, 0.f, 0.f, 0.f);
            if (row < N) v = *(const float4*)(h + (size_t)row * 64 + kc + k4);
            As[rr][k4 + 0] = v.x; As[rr][k4 + 1] = v.y; As[rr][k4 + 2] = v.z; As[rr][k4 + 3] = v.w;
        }
#pragma unroll
        for (int i = 0; i < 4; ++i) {
            int vi = i * 256 + tid;
            int k = vi >> 5;
            int c = (vi & 31) << 2;
            const float* sp = (c < 64) ? (B1 + (size_t)(kc + k) * 64 + c)
                                       : (B2 + (size_t)(kc + k) * 64 + (c - 64));
            *(float4*)&Bs[k][c] = *(const float4*)sp;
        }
        __syncthreads();
#pragma unroll
        for (int k4 = 0; k4 < 32; k4 += 4) {
            float4 a4[8];
#pragma unroll
            for (int i = 0; i < 8; ++i)
                a4[i] = *(const float4*)&As[rg * 8 + i][k4];
            float4 bv[4];
#pragma unroll
            for (int jj = 0; jj < 4; ++jj)
                bv[jj] = *(const float4*)&Bs[k4 + jj][cg * 4];
#pragma unroll
            for (int jj = 0; jj < 4; ++jj) {
#pragma unroll
                for (int i = 0; i < 8; ++i) {
                    float av = ((const float*)&a4[i])[jj];
                    acc[i][0] = fmaf(av, bv[jj].x, acc[i][0]);
                    acc[i][1] = fmaf(av, bv[jj].y, acc[i][1]);
                    acc[i][2] = fmaf(av, bv[jj].z, acc[i][2]);
                    acc[i][3] = fmaf(av, bv[jj].w, acc[i][3]);
                }
            }
        }
        __syncthreads();
    }

    int c0 = cg * 4;
    float* O; int c; const float* addp;
    if (c0 < 64) { O = O1; c = c0; addp = nullptr; }
    else         { O = O2; c = c0 - 64; addp = add2; }
    float4 av = make_float4(0.f, 0.f, 0.f, 0.f);
    if (addp) av = *(const float4*)(addp + c);
#pragma unroll
    for (int i = 0; i < 8; ++i) {
        int row = row0 + rg * 8 + i;
        if (row < N) {
            float4 o;
            o.x = acc[i][0] + av.x; o.y = acc[i][1] + av.y;
            o.z = acc[i][2] + av.z; o.w = acc[i][3] + av.w;
            *(float4*)(O + (size_t)row * 64 + c) = o;
        }
    }
}

// ---------------- final layer: agg2 + fused scorer (same producer-consumer scheme) ----------------
__global__ __launch_bounds__(256) void final_layer_kernel(
    const float* __restrict__ m, const float* __restrict__ r,
    const int* __restrict__ offs, const int* __restrict__ srcs,
    float* __restrict__ h2,
    const float* __restrict__ B1, const float* __restrict__ bias,
    const float* __restrict__ w2, const float* __restrict__ b2,
    float* __restrict__ sbuf, unsigned* __restrict__ red,
    unsigned* __restrict__ tf, int N)
{
    __shared__ float As[64][36];
    __shared__ float Bs[32][64];
    __shared__ float smax[256];
    const int tid = threadIdx.x;
    const int t = blockIdx.x / 17;
    const int j = blockIdx.x % 17;

    if (j < 16) {
        int a = 16 * t + j;
        if (a * 4 >= N) return;
        agg_body(m, r, offs, srcs, nullptr, nullptr, h2, N, a, tid);
        __syncthreads();
        if (tid == 0) bar_signal(&tf[t]);
        return;
    }

    const int row0 = t * 64;
    unsigned expected = (unsigned)((min(64, N - row0) + 3) >> 2);
    if (tid == 0) bar_wait(&tf[t], expected);
    __syncthreads();

    const int cg = tid & 31;
    const int rg = tid >> 5;
    float acc[8][2];
#pragma unroll
    for (int i = 0; i < 8; ++i) { acc[i][0] = 0.f; acc[i][1] = 0.f; }

    for (int kc = 0; kc < 64; kc += 32) {
#pragma unroll
        for (int i = 0; i < 2; ++i) {
            int vi = i * 256 + tid;
            int rr = vi >> 3;
            int k4 = (vi & 7) << 2;
            int row = row0 + rr;
            float4 v = make_float4(0.f, 0.f, 0.f, 0.f);
            if (row < N) v = *(const float4*)(h2 + (size_t)row * 64 + kc + k4);
            As[rr][k4 + 0] = v.x; As[rr][k4 + 1] = v.y; As[rr][k4 + 2] = v.z; As[rr][k4 + 3] = v.w;
        }
#pragma unroll
        for (int i = 0; i < 2; ++i) {
            int vi = i * 256 + tid;
            int k = vi >> 4;
            int c = (vi & 15) << 2;
            *(float4*)&Bs[k][c] = *(const float4*)(B1 + (size_t)(kc + k) * 64 + c);
        }
        __syncthreads();
#pragma unroll
        for (int k4 = 0; k4 < 32; k4 += 4) {
            float4 a4[8];
#pragma unroll
            for (int i = 0; i < 8; ++i)
                a4[i] = *(const float4*)&As[rg * 8 + i][k4];
            float2 bv[4];
#pragma unroll
            for (int jj = 0; jj < 4; ++jj)
                bv[jj] = *(const float2*)&Bs[k4 + jj][cg * 2];
#pragma unroll
            for (int jj = 0; jj < 4; ++jj) {
#pragma unroll
                for (int i = 0; i < 8; ++i) {
                    float av = ((const float*)&a4[i])[jj];
                    acc[i][0] = fmaf(av, bv[jj].x, acc[i][0]);
                    acc[i][1] = fmaf(av, bv[jj].y, acc[i][1]);
                }
            }
        }
        __syncthreads();
    }

    float2 av = *(const float2*)(bias + cg * 2);
    float w0 = w2[cg * 2], w1 = w2[cg * 2 + 1];
    float bb = b2[0];
    float svals[8];
#pragma unroll
    for (int i = 0; i < 8; ++i) {
        float t0 = fmaxf(acc[i][0] + av.x, 0.f);
        float t1 = fmaxf(acc[i][1] + av.y, 0.f);
        float p = fmaf(t0, w0, t1 * w1);
#pragma unroll
        for (int d = 16; d >= 1; d >>= 1) p += __shfl_xor(p, d, 64);
        svals[i] = p;
    }
    float smx = -FLT_MAX;
    if (cg == 0) {
#pragma unroll
        for (int i = 0; i < 8; ++i) {
            int row = row0 + rg * 8 + i;
            if (row < N) {
                float s = svals[i] + bb;
                sbuf[row] = s;
                smx = fmaxf(smx, s);
            }
        }
    }
    smax[tid] = smx;
    __syncthreads();
    for (int d = 128; d >= 1; d >>= 1) {
        if (tid < d) smax[tid] = fmaxf(smax[tid], smax[tid + d]);
        __syncthreads();
    }
    if (tid == 0) atomicMax(red, enc_f(smax[0]));
}

// ---------------- softmax: partials + spin barrier + normalize ----------------
__global__ __launch_bounds__(256) void softmax_kernel(
    const float* __restrict__ s, const float* __restrict__ pos,
    unsigned* __restrict__ redu, unsigned* __restrict__ arrive,
    float* __restrict__ out, int N)
{
    float* redf = (float*)redu;
    float mx = dec_f(redu[0]);
    float se = 0.f, px = 0.f, py = 0.f;
    for (int i = blockIdx.x * 256 + threadIdx.x; i < N; i += gridDim.x * 256) {
        float e = expf(s[i] - mx);
        se += e;
        px = fmaf(e, pos[2 * i], px);
        py = fmaf(e, pos[2 * i + 1], py);
    }
#pragma unroll
    for (int d = 32; d >= 1; d >>= 1) {
        se += __shfl_xor(se, d, 64);
        px += __shfl_xor(px, d, 64);
        py += __shfl_xor(py, d, 64);
    }
    if ((threadIdx.x & 63) == 0) {
        atomicAdd(&redf[1], se);
        atomicAdd(&redf[2], px);
        atomicAdd(&redf[3], py);
    }
    __syncthreads();
    if (threadIdx.x == 0) { bar_signal(arrive); bar_wait(arrive, gridDim.x); }
    __syncthreads();
    float S = redf[1];
    for (int i = blockIdx.x * 256 + threadIdx.x; i < N; i += gridDim.x * 256)
        out[2 + i] = expf(s[i] - mx) / S;
    if (blockIdx.x == 0 && threadIdx.x == 0) {
        out[0] = redf[2] / S;
        out[1] = redf[3] / S;
    }
}

extern "C" void kernel_launch(void* const* d_in, const int* in_sizes, int n_in,
                              void* d_out, int out_size, void* d_ws, size_t ws_size,
                              hipStream_t stream)
{
    const float* x    = (const float*)d_in[0];
    const float* pos  = (const float*)d_in[1];
    const int*   ei   = (const int*)d_in[2];
    const int*   qids = (const int*)d_in[3];
    const float* qrs  = (const float*)d_in[4];
    const float* emb  = (const float*)d_in[5];
    const float* ew   = (const float*)d_in[6];
    const float* eb   = (const float*)d_in[7];
    const float* Wl0  = (const float*)d_in[8];
    const float* Wr0  = (const float*)d_in[9];
    const float* b0   = (const float*)d_in[10];
    const float* Wl1  = (const float*)d_in[11];
    const float* Wr1  = (const float*)d_in[12];
    const float* b1   = (const float*)d_in[13];
    const float* Wl2  = (const float*)d_in[14];
    const float* Wr2  = (const float*)d_in[15];
    const float* b2   = (const float*)d_in[16];
    const float* sw1  = (const float*)d_in[17];
    const float* sb1  = (const float*)d_in[18];
    const float* sw2  = (const float*)d_in[19];
    const float* sb2  = (const float*)d_in[20];

    const int N  = in_sizes[0] / 128;
    const int E  = in_sizes[2] / 2;
    const int NQ = in_sizes[3];
    const int NB = (N + 255) / 256;
    const int tiles = (N + 63) / 64;

    char* base = (char*)d_ws;
    size_t wsoff = 0;
    auto take = [&](size_t bytes) -> char* {
        char* p = base + wsoff;
        wsoff = (wsoff + bytes + 255) & ~(size_t)255;
        return p;
    };
    // zeroed region: deg[N] | bar[8] | red[8] | tf1[tiles] | tf2[tiles] | tf3[tiles]
    size_t zcount = (size_t)N + 16 + 3 * (size_t)tiles;
    int*      zreg   = (int*)take(zcount * 4);
    int*      deg    = zreg;
    unsigned* bar    = (unsigned*)(zreg + N);
    unsigned* red    = bar + 8;
    unsigned* tf1    = red + 8;
    unsigned* tf2    = tf1 + tiles;
    unsigned* tf3    = tf2 + tiles;
    int*      offs   = (int*)take((size_t)(N + 1) * 4);
    int*      cursor = (int*)take((size_t)N * 4);
    int*      bsum   = (int*)take((size_t)NB * 4);
    int*      bbase  = (int*)take((size_t)NB * 4);
    int*      srcs   = (int*)take((size_t)E * 4);
    float*    zout   = (float*)take(192 * 4);       // zq[64], cl[64], crb[64]
    float*    mbuf   = (float*)take((size_t)N * 64 * 4);
    float*    rbuf   = (float*)take((size_t)N * 64 * 4);
    float*    m2     = (float*)take((size_t)N * 64 * 4);
    float*    r2     = (float*)take((size_t)N * 64 * 4);
    float*    hbuf   = (float*)take((size_t)N * 64 * 4);
    float*    sbuf   = (float*)take((size_t)N * 4);
    (void)ws_size; (void)n_in; (void)out_size;

    const int* esrc = ei;
    const int* edst = ei + E;

    hipMemsetAsync(zreg, 0, zcount * 4, stream);

    int schunks = (E + 4095) / 4096;
    int nCount = schunks * 8;
    int extra = nCount - 2 * tiles; if (extra < 0) extra = 0;
    int total0 = 3 * tiles + extra + 1;

    // mega0: interleaved count + gemm0 + encoder (mbuf = x@Wl0_top, rbuf = x@Wr0_top)
    mega0_kernel<<<total0, 256, 0, stream>>>(edst, deg, E, N, nCount, tiles,
                                             qids, qrs, emb, ew, eb, Wl0, Wr0, b0, zout, NQ,
                                             x, mbuf, rbuf);
    scan_kernel<<<NB, 256, 0, stream>>>(deg, offs, cursor, bsum, bbase, bar, N, NB);
    scatter_kernel<<<nCount, 256, 0, stream>>>(esrc, edst, cursor, srcs, E, N);

    // D1: agg0 (+cl, +crb) -> hbuf  ||  gemm1: m2 = h0@Wl1, r2 = h0@Wr1 + b1
    layer_kernel<<<tiles * 17, 256, 0, stream>>>(mbuf, rbuf, offs, srcs, zout + 64, zout + 128,
                                                 hbuf, Wl1, Wr1, b1, m2, r2, tf1, N);
    // D2: agg1 -> hbuf  ||  gemm2: mbuf = h1@Wl2, rbuf = h1@Wr2 + b2
    layer_kernel<<<tiles * 17, 256, 0, stream>>>(m2, r2, offs, srcs, nullptr, nullptr,
                                                 hbuf, Wl2, Wr2, b2, mbuf, rbuf, tf2, N);
    // D3: agg2 -> m2 (h2 storage)  ||  scorer -> sbuf + atomicMax red[0]
    final_layer_kernel<<<tiles * 17, 256, 0, stream>>>(mbuf, rbuf, offs, srcs, m2,
                                                       sw1, sb1, sw2, sb2, sbuf, red, tf3, N);
    // softmax (arrive counter = bar[2])
    softmax_kernel<<<128, 256, 0, stream>>>(sbuf, pos, red, bar + 2, (float*)d_out, N);
}

// Round 13
// 400.171 us; speedup vs baseline: 5.8263x; 5.8263x over previous
//
#include <hip/hip_runtime.h>
#include <cmath>
#include <cfloat>

#define DEV __device__ __forceinline__

DEV unsigned enc_f(float x) { unsigned u = __float_as_uint(x); return (u >> 31) ? ~u : (u | 0x80000000u); }
DEV float dec_f(unsigned u) { return __uint_as_float((u >> 31) ? (u & 0x7FFFFFFFu) : ~u); }

// ---------------- XCD-partitioned degree count (+ encoder in last block) ----------------
__global__ __launch_bounds__(256) void enc_count_kernel(
    const int* __restrict__ dst, int* __restrict__ deg, int E, int N, int nCount,
    const int* __restrict__ ids, const float* __restrict__ rssi,
    const float* __restrict__ emb, const float* __restrict__ ew, const float* __restrict__ eb,
    const float* __restrict__ Wl0, const float* __restrict__ Wr0, const float* __restrict__ b0,
    float* __restrict__ zout, int NQ)
{
    if (blockIdx.x < (unsigned)nCount) {
        const int part = blockIdx.x & 7;
        const int chunk = blockIdx.x >> 3;
        const int npart = (N + 7) >> 3;
        const int lo = part * npart;
        const int hi = min(lo + npart, N);
        const int base = chunk * 4096 + threadIdx.x;
#pragma unroll
        for (int it = 0; it < 16; ++it) {
            int i = base + it * 256;
            if (i < E) {
                int d = dst[i];
                if (d >= lo && d < hi) atomicAdd(&deg[d], 1);
            }
        }
        return;
    }
    __shared__ float zsh[4][64];
    __shared__ float zq[64];
    int j = threadIdx.x & 63;
    int g = threadIdx.x >> 6;
    float acc = 0.f;
    for (int q = g; q < NQ; q += 4) {
        int id = ids[q];
        const float* e = emb + (size_t)id * 32;
        float p = eb[j];
#pragma unroll
        for (int k = 0; k < 32; ++k) p = fmaf(e[k], ew[k * 64 + j], p);
        p = fmaf(rssi[q], ew[32 * 64 + j], p);
        acc += fmaxf(p, 0.f);
    }
    zsh[g][j] = acc;
    __syncthreads();
    if (g == 0) {
        float z = (zsh[0][j] + zsh[1][j] + zsh[2][j] + zsh[3][j]) / (float)NQ;
        zq[j] = z;
        zout[j] = z;
    }
    __syncthreads();
    if (g == 0) {
        float cl = 0.f, cr = 0.f;
        for (int k = 0; k < 64; ++k) {
            float zk = zq[k];
            cl = fmaf(zk, Wl0[(128 + k) * 64 + j], cl);
            cr = fmaf(zk, Wr0[(128 + k) * 64 + j], cr);
        }
        zout[64 + j] = cl;
        zout[128 + j] = cr + b0[j];
    }
}

// ---------------- CSR build: multi-block scan ----------------
__global__ __launch_bounds__(256) void scanA_kernel(const int* __restrict__ deg, int* __restrict__ offs,
                                                    int* __restrict__ bsum, int N)
{
    __shared__ int sh[256];
    int t = threadIdx.x;
    int i = blockIdx.x * 256 + t;
    int v = (i < N) ? deg[i] : 0;
    sh[t] = v;
    __syncthreads();
#pragma unroll
    for (int d = 1; d < 256; d <<= 1) {
        int u = (t >= d) ? sh[t - d] : 0;
        __syncthreads();
        sh[t] += u;
        __syncthreads();
    }
    if (i < N) offs[i] = sh[t] - v;
    if (t == 255) bsum[blockIdx.x] = sh[255];
}

// scanB also zero-inits red[0..7] ([0]=max [1]=sum [2]=px [3]=py)
__global__ __launch_bounds__(256) void scanB_kernel(const int* __restrict__ bsum, int* __restrict__ bbase,
                                                    int* __restrict__ offs, unsigned* __restrict__ red,
                                                    int NB, int N)
{
    __shared__ int sh[256];
    int t = threadIdx.x;
    if (t < 8) red[t] = 0u;
    int C = (NB + 255) >> 8;
    int c0 = t * C, c1 = min(c0 + C, NB);
    int s = 0;
    for (int i = c0; i < c1; ++i) s += bsum[i];
    sh[t] = s;
    __syncthreads();
#pragma unroll
    for (int d = 1; d < 256; d <<= 1) {
        int u = (t >= d) ? sh[t - d] : 0;
        __syncthreads();
        sh[t] += u;
        __syncthreads();
    }
    int run = (t > 0) ? sh[t - 1] : 0;
    for (int i = c0; i < c1; ++i) { bbase[i] = run; run += bsum[i]; }
    if (t == 255) offs[N] = sh[255];
}

__global__ __launch_bounds__(256) void scanC_kernel(int* __restrict__ offs, int* __restrict__ cursor,
                                                    const int* __restrict__ bbase, int N)
{
    int i = blockIdx.x * 256 + threadIdx.x;
    if (i < N) {
        int o = offs[i] + bbase[blockIdx.x];
        offs[i] = o;
        cursor[i] = o;
    }
}

// XCD-partitioned scatter (round-2 win): one XCD owns each srcs region.
__global__ __launch_bounds__(256) void scatter_kernel(const int* __restrict__ src, const int* __restrict__ dst,
                                                      int* __restrict__ cursor, int* __restrict__ srcs,
                                                      int E, int N)
{
    const int part = blockIdx.x & 7;
    const int chunk = blockIdx.x >> 3;
    const int npart = (N + 7) >> 3;
    const int lo = part * npart;
    const int hi = min(lo + npart, N);
    const int base = chunk * 4096 + threadIdx.x;
#pragma unroll
    for (int it = 0; it < 16; ++it) {
        int i = base + it * 256;
        if (i < E) {
            int d = dst[i];
            if (d >= lo && d < hi) {
                int p = atomicAdd(&cursor[d], 1);
                srcs[p] = src[i];
            }
        }
    }
}

// ---------------- GEMM (dual out): O1 = A@B1, O2 = A@B2 + add2 ----------------
// 32-row x 128-col tile, 256 thr (~6 blocks/CU). A row-major in LDS: staging stores
// uniform 4/bank, inner-loop A reads are half-wave broadcasts (free).
template <int K>
__global__ __launch_bounds__(256) void gemm_kernel(
    const float* __restrict__ A, const float* __restrict__ B1, const float* __restrict__ B2,
    const float* __restrict__ add2,
    float* __restrict__ O1, float* __restrict__ O2, int N)
{
    __shared__ float As[32][36];
    __shared__ float Bs[32][128];

    const int tid = threadIdx.x;
    const int cg = tid & 31;
    const int rg = tid >> 5;
    const int row0 = blockIdx.x * 32;

    float acc[4][4];
#pragma unroll
    for (int i = 0; i < 4; ++i)
#pragma unroll
        for (int j = 0; j < 4; ++j) acc[i][j] = 0.f;

    for (int kc = 0; kc < K; kc += 32) {
        {
            int r = tid >> 3;
            int k4 = (tid & 7) << 2;
            int row = row0 + r;
            float4 v = make_float4(0.f, 0.f, 0.f, 0.f);
            if (row < N) v = *(const float4*)(A + (size_t)row * K + kc + k4);
            As[r][k4 + 0] = v.x; As[r][k4 + 1] = v.y; As[r][k4 + 2] = v.z; As[r][k4 + 3] = v.w;
        }
#pragma unroll
        for (int i = 0; i < 4; ++i) {
            int vi = i * 256 + tid;
            int k = vi >> 5;
            int c = (vi & 31) << 2;
            const float* sp = (c < 64) ? (B1 + (size_t)(kc + k) * 64 + c)
                                       : (B2 + (size_t)(kc + k) * 64 + (c - 64));
            *(float4*)&Bs[k][c] = *(const float4*)sp;
        }
        __syncthreads();
#pragma unroll
        for (int k4 = 0; k4 < 32; k4 += 4) {
            float4 a4[4];
#pragma unroll
            for (int i = 0; i < 4; ++i)
                a4[i] = *(const float4*)&As[rg * 4 + i][k4];
            float4 bv[4];
#pragma unroll
            for (int j = 0; j < 4; ++j)
                bv[j] = *(const float4*)&Bs[k4 + j][cg * 4];
#pragma unroll
            for (int j = 0; j < 4; ++j) {
#pragma unroll
                for (int i = 0; i < 4; ++i) {
                    float av = ((const float*)&a4[i])[j];
                    acc[i][0] = fmaf(av, bv[j].x, acc[i][0]);
                    acc[i][1] = fmaf(av, bv[j].y, acc[i][1]);
                    acc[i][2] = fmaf(av, bv[j].z, acc[i][2]);
                    acc[i][3] = fmaf(av, bv[j].w, acc[i][3]);
                }
            }
        }
        __syncthreads();
    }

    int c0 = cg * 4;
    float* O; int c; const float* addp;
    if (c0 < 64) { O = O1; c = c0; addp = nullptr; }
    else         { O = O2; c = c0 - 64; addp = add2; }
    float4 av = make_float4(0.f, 0.f, 0.f, 0.f);
    if (addp) av = *(const float4*)(addp + c);
#pragma unroll
    for (int i = 0; i < 4; ++i) {
        int row = row0 + rg * 4 + i;
        if (row < N) {
            float4 o;
            o.x = acc[i][0] + av.x; o.y = acc[i][1] + av.y;
            o.z = acc[i][2] + av.z; o.w = acc[i][3] + av.w;
            *(float4*)(O + (size_t)row * 64 + c) = o;
        }
    }
}

// ---------------- aggregation: h = relu(segsum(m)/clip(deg,1) + [deg>0]*cl + r) ----------------
// wave per node, 64 lanes = 64 features, 16 gathers in flight (at gather-BW floor).
__global__ __launch_bounds__(256) void agg_kernel(
    const float* __restrict__ m, const float* __restrict__ r,
    const int* __restrict__ off, const int* __restrict__ srcs,
    const float* __restrict__ cl, float* __restrict__ hout, int N)
{
    int node = blockIdx.x * 4 + threadIdx.y;
    if (node >= N) return;
    int lane = threadIdx.x;
    int e0 = off[node], e1 = off[node + 1];
    float a[16];
#pragma unroll
    for (int i = 0; i < 16; ++i) a[i] = 0.f;

    for (int base = e0; base < e1; base += 64) {
        int e = base + lane;
        int sv = (e < e1) ? srcs[e] : 0;
        int cnt = min(e1 - base, 64);
        int j = 0;
        for (; j + 16 <= cnt; j += 16) {
#pragma unroll
            for (int u = 0; u < 16; ++u) {
                int s = __shfl(sv, j + u);
                a[u] += m[(size_t)s * 64 + lane];
            }
        }
        for (; j + 4 <= cnt; j += 4) {
#pragma unroll
            for (int u = 0; u < 4; ++u) {
                int s = __shfl(sv, j + u);
                a[u] += m[(size_t)s * 64 + lane];
            }
        }
        for (; j < cnt; ++j) {
            int s = __shfl(sv, j);
            a[0] += m[(size_t)s * 64 + lane];
        }
    }
    float sum = 0.f;
#pragma unroll
    for (int i = 0; i < 16; ++i) sum += a[i];
    int deg = e1 - e0;
    float v = sum / (float)(deg > 0 ? deg : 1) + r[(size_t)node * 64 + lane];
    if (cl != nullptr && deg > 0) v += cl[lane];
    hout[(size_t)node * 64 + lane] = fmaxf(v, 0.f);
}

// ---------------- fused scorer: s = relu(h@w1+b1)@w2 + b2, block max -> atomicMax ----------------
__global__ __launch_bounds__(256) void scorer_gemm_kernel(
    const float* __restrict__ A, const float* __restrict__ B1,
    const float* __restrict__ bias, const float* __restrict__ w2, const float* __restrict__ b2,
    float* __restrict__ sbuf, unsigned* __restrict__ red, int N)
{
    __shared__ float As[32][36];
    __shared__ float Bs[32][64];
    __shared__ float smax[256];

    const int tid = threadIdx.x;
    const int cg = tid & 31;
    const int rg = tid >> 5;
    const int row0 = blockIdx.x * 32;

    float acc[4][2];
#pragma unroll
    for (int i = 0; i < 4; ++i) { acc[i][0] = 0.f; acc[i][1] = 0.f; }

    for (int kc = 0; kc < 64; kc += 32) {
        {
            int r = tid >> 3;
            int k4 = (tid & 7) << 2;
            int row = row0 + r;
            float4 v = make_float4(0.f, 0.f, 0.f, 0.f);
            if (row < N) v = *(const float4*)(A + (size_t)row * 64 + kc + k4);
            As[r][k4 + 0] = v.x; As[r][k4 + 1] = v.y; As[r][k4 + 2] = v.z; As[r][k4 + 3] = v.w;
        }
#pragma unroll
        for (int i = 0; i < 2; ++i) {
            int vi = i * 256 + tid;
            int k = vi >> 4;
            int c = (vi & 15) << 2;
            *(float4*)&Bs[k][c] = *(const float4*)(B1 + (size_t)(kc + k) * 64 + c);
        }
        __syncthreads();
#pragma unroll
        for (int k4 = 0; k4 < 32; k4 += 4) {
            float4 a4[4];
#pragma unroll
            for (int i = 0; i < 4; ++i)
                a4[i] = *(const float4*)&As[rg * 4 + i][k4];
            float2 bv[4];
#pragma unroll
            for (int j = 0; j < 4; ++j)
                bv[j] = *(const float2*)&Bs[k4 + j][cg * 2];
#pragma unroll
            for (int j = 0; j < 4; ++j) {
#pragma unroll
                for (int i = 0; i < 4; ++i) {
                    float av = ((const float*)&a4[i])[j];
                    acc[i][0] = fmaf(av, bv[j].x, acc[i][0]);
                    acc[i][1] = fmaf(av, bv[j].y, acc[i][1]);
                }
            }
        }
        __syncthreads();
    }

    float2 av = *(const float2*)(bias + cg * 2);
    float w0 = w2[cg * 2], w1 = w2[cg * 2 + 1];
    float bb = b2[0];
    float svals[4];
#pragma unroll
    for (int i = 0; i < 4; ++i) {
        float t0 = fmaxf(acc[i][0] + av.x, 0.f);
        float t1 = fmaxf(acc[i][1] + av.y, 0.f);
        float p = fmaf(t0, w0, t1 * w1);
#pragma unroll
        for (int d = 16; d >= 1; d >>= 1) p += __shfl_xor(p, d, 64);
        svals[i] = p;
    }
    float smx = -FLT_MAX;
    if (cg == 0) {
#pragma unroll
        for (int i = 0; i < 4; ++i) {
            int row = row0 + rg * 4 + i;
            if (row < N) {
                float s = svals[i] + bb;
                sbuf[row] = s;
                smx = fmaxf(smx, s);
            }
        }
    }
    smax[tid] = smx;
    __syncthreads();
    for (int d = 128; d >= 1; d >>= 1) {
        if (tid < d) smax[tid] = fmaxf(smax[tid], smax[tid + d]);
        __syncthreads();
    }
    if (tid == 0) atomicMax(red, enc_f(smax[0]));
}

// ---------------- softmax reductions ----------------
__global__ __launch_bounds__(256) void sum_kernel(const float* __restrict__ s, const float* __restrict__ pos,
                                                  const unsigned* __restrict__ redmax, float* __restrict__ red, int N)
{
    float mx = dec_f(redmax[0]);
    float se = 0.f, px = 0.f, py = 0.f;
    for (int i = blockIdx.x * blockDim.x + threadIdx.x; i < N; i += gridDim.x * blockDim.x) {
        float e = expf(s[i] - mx);
        se += e;
        px = fmaf(e, pos[2 * i], px);
        py = fmaf(e, pos[2 * i + 1], py);
    }
#pragma unroll
    for (int d = 32; d >= 1; d >>= 1) {
        se += __shfl_xor(se, d, 64);
        px += __shfl_xor(px, d, 64);
        py += __shfl_xor(py, d, 64);
    }
    if ((threadIdx.x & 63) == 0) {
        atomicAdd(&red[1], se);
        atomicAdd(&red[2], px);
        atomicAdd(&red[3], py);
    }
}

__global__ __launch_bounds__(256) void final_kernel(const float* __restrict__ s, const unsigned* __restrict__ redmax,
                                                    const float* __restrict__ red, float* __restrict__ out, int N)
{
    float mx = dec_f(redmax[0]);
    float S = red[1];
    int i = blockIdx.x * blockDim.x + threadIdx.x;
    if (i < N) out[2 + i] = expf(s[i] - mx) / S;
    if (i == 0) {
        out[0] = red[2] / S;
        out[1] = red[3] / S;
    }
}

extern "C" void kernel_launch(void* const* d_in, const int* in_sizes, int n_in,
                              void* d_out, int out_size, void* d_ws, size_t ws_size,
                              hipStream_t stream)
{
    const float* x    = (const float*)d_in[0];
    const float* pos  = (const float*)d_in[1];
    const int*   ei   = (const int*)d_in[2];
    const int*   qids = (const int*)d_in[3];
    const float* qrs  = (const float*)d_in[4];
    const float* emb  = (const float*)d_in[5];
    const float* ew   = (const float*)d_in[6];
    const float* eb   = (const float*)d_in[7];
    const float* Wl0  = (const float*)d_in[8];
    const float* Wr0  = (const float*)d_in[9];
    const float* b0   = (const float*)d_in[10];
    const float* Wl1  = (const float*)d_in[11];
    const float* Wr1  = (const float*)d_in[12];
    const float* b1   = (const float*)d_in[13];
    const float* Wl2  = (const float*)d_in[14];
    const float* Wr2  = (const float*)d_in[15];
    const float* b2   = (const float*)d_in[16];
    const float* sw1  = (const float*)d_in[17];
    const float* sb1  = (const float*)d_in[18];
    const float* sw2  = (const float*)d_in[19];
    const float* sb2  = (const float*)d_in[20];

    const int N  = in_sizes[0] / 128;
    const int E  = in_sizes[2] / 2;
    const int NQ = in_sizes[3];
    const int NB = (N + 255) / 256;

    char* base = (char*)d_ws;
    size_t wsoff = 0;
    auto take = [&](size_t bytes) -> char* {
        char* p = base + wsoff;
        wsoff = (wsoff + bytes + 255) & ~(size_t)255;
        return p;
    };
    int*      deg    = (int*)take((size_t)N * 4);
    int*      offs   = (int*)take((size_t)(N + 1) * 4);
    int*      cursor = (int*)take((size_t)N * 4);
    int*      bsum   = (int*)take((size_t)NB * 4);
    int*      bbase  = (int*)take((size_t)NB * 4);
    int*      srcs   = (int*)take((size_t)E * 4);
    float*    zout   = (float*)take(192 * 4);   // zq[64], cl[64], crb[64]
    unsigned* red    = (unsigned*)take(32);     // [0]=max [1]=sumexp [2]=px [3]=py
    float*    mbuf   = (float*)take((size_t)N * 64 * 4);
    float*    rbuf   = (float*)take((size_t)N * 64 * 4);
    float*    hbuf   = (float*)take((size_t)N * 64 * 4);
    float*    sbuf   = (float*)take((size_t)N * 4);
    (void)ws_size; (void)n_in; (void)out_size;

    const int* esrc = ei;
    const int* edst = ei + E;

    hipMemsetAsync(deg, 0, (size_t)N * 4, stream);

    int schunks = (E + 4095) / 4096;
    int nCount = schunks * 8;
    enc_count_kernel<<<nCount + 1, 256, 0, stream>>>(edst, deg, E, N, nCount,
                                                     qids, qrs, emb, ew, eb, Wl0, Wr0, b0, zout, NQ);
    scanA_kernel<<<NB, 256, 0, stream>>>(deg, offs, bsum, N);
    scanB_kernel<<<1, 256, 0, stream>>>(bsum, bbase, offs, red, NB, N);
    scanC_kernel<<<NB, 256, 0, stream>>>(offs, cursor, bbase, N);
    scatter_kernel<<<schunks * 8, 256, 0, stream>>>(esrc, edst, cursor, srcs, E, N);

    int gblocks = (N + 31) / 32;
    dim3 ablk(64, 4);
    int ablocks = (N + 3) / 4;

    // layer 0: mbuf = x@Wl0_top, rbuf = x@Wr0_top + (zq@Wr0_bot + b0)
    gemm_kernel<128><<<gblocks, 256, 0, stream>>>(x, Wl0, Wr0, zout + 128, mbuf, rbuf, N);
    agg_kernel<<<ablocks, ablk, 0, stream>>>(mbuf, rbuf, offs, srcs, zout + 64, hbuf, N);
    // layer 1
    gemm_kernel<64><<<gblocks, 256, 0, stream>>>(hbuf, Wl1, Wr1, b1, mbuf, rbuf, N);
    agg_kernel<<<ablocks, ablk, 0, stream>>>(mbuf, rbuf, offs, srcs, nullptr, hbuf, N);
    // layer 2
    gemm_kernel<64><<<gblocks, 256, 0, stream>>>(hbuf, Wl2, Wr2, b2, mbuf, rbuf, N);
    agg_kernel<<<ablocks, ablk, 0, stream>>>(mbuf, rbuf, offs, srcs, nullptr, hbuf, N);
    // fused scorer (writes sbuf + atomicMax into red[0])
    scorer_gemm_kernel<<<gblocks, 256, 0, stream>>>(hbuf, sw1, sb1, sw2, sb2, sbuf, red, N);

    sum_kernel<<<128, 256, 0, stream>>>(sbuf, pos, red, (float*)red, N);
    final_kernel<<<(N + 255) / 256, 256, 0, stream>>>(sbuf, red, (float*)red, (float*)d_out, N);
}